// Round 4
// baseline (612.630 us; speedup 1.0000x reference)
//
#include <hip/hip_runtime.h>
#include <hip/hip_bf16.h>
#include <math.h>

#define NEG_SLOPE 0.2f

typedef __attribute__((ext_vector_type(8))) short short8;
typedef __attribute__((ext_vector_type(4))) float float4v;

__device__ __forceinline__ unsigned f2bf(float f) {
  unsigned u = __builtin_bit_cast(unsigned, f);
  return (u + 0x7fffu + ((u >> 16) & 1u)) >> 16;  // RNE
}
__device__ __forceinline__ float bflo(unsigned u) {
  return __builtin_bit_cast(float, u << 16);
}
__device__ __forceinline__ float bfhi(unsigned u) {
  return __builtin_bit_cast(float, u & 0xffff0000u);
}

// ---------------- weight pre-transpose: Wt[c][k] bf16, c in [0,256) --------
__global__ __launch_bounds__(256) void convert_w(const float* __restrict__ W1,
                                                 const float* __restrict__ Wp,
                                                 short* __restrict__ Wt) {
  int k = blockIdx.x;   // 0..767
  int c = threadIdx.x;  // 0..255
  float v = (c < 128) ? W1[k * 128 + c] : Wp[k * 128 + (c - 128)];
  Wt[(size_t)c * 768 + k] = (short)f2bf(v);
}

// ------- bf16 MFMA GEMM + fused attn1: emits h1bf, a_s1, a_d1, proj -------
// BM=128, BN=256, BK=32, 256 thr (4 waves). Waves 0-1: h1 cols (0..127)
// -> h1bf pack + attention logit reductions. Waves 2-3: proj cols.
__global__ __launch_bounds__(256) void gemm_mfma(
    const float* __restrict__ x, const short* __restrict__ Wt,
    const float* __restrict__ att_src1, const float* __restrict__ att_dst1,
    float* __restrict__ proj, unsigned* __restrict__ h1bf,
    float* __restrict__ a_s1, float* __restrict__ a_d1) {
  __shared__ short As[128][40];
  __shared__ short Bs[256][40];
  const int tid = threadIdx.x;
  const int wave = tid >> 6, lane = tid & 63;
  const int l15 = lane & 15, l4 = lane >> 4;
  const int row0 = blockIdx.x * 128;

  const int ar = tid >> 3;
  const int ak = (tid & 7) * 4;
  const int bc = tid >> 2;
  const int bk = (tid & 3) * 8;

  float4v acc[8][4] = {};

  for (int k0 = 0; k0 < 768; k0 += 32) {
#pragma unroll
    for (int i = 0; i < 4; i++) {
      int r = i * 32 + ar;
      float4 f = *(const float4*)&x[(size_t)(row0 + r) * 768 + k0 + ak];
      uint2 p;
      p.x = f2bf(f.x) | (f2bf(f.y) << 16);
      p.y = f2bf(f.z) | (f2bf(f.w) << 16);
      *(uint2*)&As[r][ak] = p;
    }
#pragma unroll
    for (int i = 0; i < 4; i++) {
      int c = i * 64 + bc;
      uint4 v = *(const uint4*)&Wt[(size_t)c * 768 + k0 + bk];
      *(uint4*)&Bs[c][bk] = v;
    }
    __syncthreads();

    short8 afr[8];
#pragma unroll
    for (int rt = 0; rt < 8; rt++)
      afr[rt] = *(const short8*)&As[rt * 16 + l15][l4 * 8];
#pragma unroll
    for (int ct = 0; ct < 4; ct++) {
      short8 bfr = *(const short8*)&Bs[wave * 64 + ct * 16 + l15][l4 * 8];
#pragma unroll
      for (int rt = 0; rt < 8; rt++)
        acc[rt][ct] =
            __builtin_amdgcn_mfma_f32_16x16x32_bf16(afr[rt], bfr, acc[rt][ct], 0, 0, 0);
    }
    __syncthreads();
  }

  const int colbase = wave * 64;
  if (wave < 2) {
    // h1 columns: pack bf16 + attention logits
#pragma unroll
    for (int ct = 0; ct < 4; ct++) {
      const int c = colbase + ct * 16 + l15;
      const int head = wave * 4 + ct;
      const float asw = att_src1[c];
      const float adw = att_dst1[c];
#pragma unroll
      for (int rt = 0; rt < 8; rt++) {
#pragma unroll
        for (int r = 0; r < 4; r++) {
          const int R = row0 + rt * 16 + l4 * 4 + r;
          const float v = acc[rt][ct][r];
          unsigned u = f2bf(v);
          unsigned up = __shfl_xor(u, 1);
          if ((l15 & 1) == 0) h1bf[(size_t)R * 64 + (c >> 1)] = u | (up << 16);
          float as = v * asw, ad = v * adw;
#pragma unroll
          for (int off = 8; off; off >>= 1) {
            as += __shfl_xor(as, off);
            ad += __shfl_xor(ad, off);
          }
          if (l15 == 0) {
            a_s1[R * 8 + head] = as;
            a_d1[R * 8 + head] = ad;
          }
        }
      }
    }
  } else {
    // proj columns
#pragma unroll
    for (int ct = 0; ct < 4; ct++) {
      const int c = colbase - 128 + ct * 16 + l15;
#pragma unroll
      for (int rt = 0; rt < 8; rt++) {
#pragma unroll
        for (int r = 0; r < 4; r++) {
          const int R = row0 + rt * 16 + l4 * 4 + r;
          proj[(size_t)R * 128 + c] = acc[rt][ct][r];
        }
      }
    }
  }
}

// ---------------- counting sort of edges by dst ----------------------------
__global__ void init_counts(int* counts, int N) {
  int i = blockIdx.x * blockDim.x + threadIdx.x;
  if (i < N) counts[i] = 1;  // self loop
}

__global__ void hist_kernel(const int* __restrict__ dst, int* counts, int E) {
  int i = blockIdx.x * blockDim.x + threadIdx.x;
  int base = i * 4;
  if (base + 3 < E) {
    int4 d = *(const int4*)&dst[base];
    atomicAdd(&counts[d.x], 1);
    atomicAdd(&counts[d.y], 1);
    atomicAdd(&counts[d.z], 1);
    atomicAdd(&counts[d.w], 1);
  } else {
    for (int j = base; j < E; j++) atomicAdd(&counts[dst[j]], 1);
  }
}

__global__ __launch_bounds__(256) void scan_a(const int* __restrict__ counts,
                                              int* offsets, int* bsum) {
  __shared__ int s[256];
  int t = threadIdx.x, idx = blockIdx.x * 256 + t;
  int v = counts[idx];
  s[t] = v;
  __syncthreads();
  for (int d = 1; d < 256; d <<= 1) {
    int x = (t >= d) ? s[t - d] : 0;
    __syncthreads();
    s[t] += x;
    __syncthreads();
  }
  offsets[idx] = s[t] - v;
  if (t == 255) bsum[blockIdx.x] = s[t];
}

__global__ __launch_bounds__(256) void scan_b(int* bsum) {
  __shared__ int s[256];
  int t = threadIdx.x;
  int v = bsum[t];
  s[t] = v;
  __syncthreads();
  for (int d = 1; d < 256; d <<= 1) {
    int x = (t >= d) ? s[t - d] : 0;
    __syncthreads();
    s[t] += x;
    __syncthreads();
  }
  bsum[t] = s[t] - v;
}

// also places the self-loop at segment start (replaces scatter_self)
__global__ __launch_bounds__(256) void scan_c(int* offsets, const int* bsum,
                                              int* cursor, int* sortedsrc,
                                              int N, int Etot) {
  int t = threadIdx.x, idx = blockIdx.x * 256 + t;
  int off = offsets[idx] + bsum[blockIdx.x];
  offsets[idx] = off;
  sortedsrc[off] = idx;
  cursor[idx] = off + 1;
  if (idx == 0) offsets[N] = Etot;
}

__global__ void scatter_edges(const int* __restrict__ src,
                              const int* __restrict__ dst, int* cursor,
                              int* sortedsrc, int E) {
  int i = blockIdx.x * blockDim.x + threadIdx.x;
  int base = i * 4;
  if (base + 3 < E) {
    int4 s = *(const int4*)&src[base];
    int4 d = *(const int4*)&dst[base];
    sortedsrc[atomicAdd(&cursor[d.x], 1)] = s.x;
    sortedsrc[atomicAdd(&cursor[d.y], 1)] = s.y;
    sortedsrc[atomicAdd(&cursor[d.z], 1)] = s.z;
    sortedsrc[atomicAdd(&cursor[d.w], 1)] = s.w;
  } else {
    for (int j = base; j < E; j++)
      sortedsrc[atomicAdd(&cursor[dst[j]], 1)] = src[j];
  }
}

// ------- layer-1 aggregation + residual + ELU + layer-2 features -----------
// 16 nodes/block (256 thr), 16 lanes/node, 8 channels/lane (uint4 gathers),
// 4-deep edge pipeline.
__global__ __launch_bounds__(256) void agg1_fused(
    const uint4* __restrict__ h1bf4, const float* __restrict__ proj,
    const float* __restrict__ a_s1, const float* __restrict__ a_d1,
    const int* __restrict__ offsets, const int* __restrict__ sortedsrc,
    const float* __restrict__ b1, const float* __restrict__ bp,
    const float* __restrict__ W2, const float* __restrict__ att_s2,
    const float* __restrict__ att_d2, float* __restrict__ h2,
    float* __restrict__ as2, float* __restrict__ ad2) {
  const int t = threadIdx.x;
  const int n = blockIdx.x * 16 + (t >> 4);
  const int k = t & 15;   // lane within node: channels 8k..8k+7
  const int hd = k >> 1;  // head
  const float ad = a_d1[n * 8 + hd];
  const int begin = offsets[n], end = offsets[n + 1];
  float acc[8] = {};
  float aw = 0.f;
  int j = begin;
  for (; j + 4 <= end; j += 4) {
    int s0 = sortedsrc[j], s1 = sortedsrc[j + 1];
    int s2 = sortedsrc[j + 2], s3 = sortedsrc[j + 3];
    float e0 = a_s1[s0 * 8 + hd], e1 = a_s1[s1 * 8 + hd];
    float e2 = a_s1[s2 * 8 + hd], e3 = a_s1[s3 * 8 + hd];
    uint4 q0 = h1bf4[(size_t)s0 * 16 + k];
    uint4 q1 = h1bf4[(size_t)s1 * 16 + k];
    uint4 q2 = h1bf4[(size_t)s2 * 16 + k];
    uint4 q3 = h1bf4[(size_t)s3 * 16 + k];
    e0 += ad; e1 += ad; e2 += ad; e3 += ad;
    float w0 = __expf(e0 > 0.f ? e0 : NEG_SLOPE * e0);
    float w1 = __expf(e1 > 0.f ? e1 : NEG_SLOPE * e1);
    float w2 = __expf(e2 > 0.f ? e2 : NEG_SLOPE * e2);
    float w3 = __expf(e3 > 0.f ? e3 : NEG_SLOPE * e3);
    acc[0] += w0 * bflo(q0.x) + w1 * bflo(q1.x) + w2 * bflo(q2.x) + w3 * bflo(q3.x);
    acc[1] += w0 * bfhi(q0.x) + w1 * bfhi(q1.x) + w2 * bfhi(q2.x) + w3 * bfhi(q3.x);
    acc[2] += w0 * bflo(q0.y) + w1 * bflo(q1.y) + w2 * bflo(q2.y) + w3 * bflo(q3.y);
    acc[3] += w0 * bfhi(q0.y) + w1 * bfhi(q1.y) + w2 * bfhi(q2.y) + w3 * bfhi(q3.y);
    acc[4] += w0 * bflo(q0.z) + w1 * bflo(q1.z) + w2 * bflo(q2.z) + w3 * bflo(q3.z);
    acc[5] += w0 * bfhi(q0.z) + w1 * bfhi(q1.z) + w2 * bfhi(q2.z) + w3 * bfhi(q3.z);
    acc[6] += w0 * bflo(q0.w) + w1 * bflo(q1.w) + w2 * bflo(q2.w) + w3 * bflo(q3.w);
    acc[7] += w0 * bfhi(q0.w) + w1 * bfhi(q1.w) + w2 * bfhi(q2.w) + w3 * bfhi(q3.w);
    aw += (w0 + w1) + (w2 + w3);
  }
  for (; j < end; j++) {
    int s0 = sortedsrc[j];
    float e0 = a_s1[s0 * 8 + hd] + ad;
    uint4 q0 = h1bf4[(size_t)s0 * 16 + k];
    float w0 = __expf(e0 > 0.f ? e0 : NEG_SLOPE * e0);
    acc[0] += w0 * bflo(q0.x);
    acc[1] += w0 * bfhi(q0.x);
    acc[2] += w0 * bflo(q0.y);
    acc[3] += w0 * bfhi(q0.y);
    acc[4] += w0 * bflo(q0.z);
    acc[5] += w0 * bfhi(q0.z);
    acc[6] += w0 * bflo(q0.w);
    acc[7] += w0 * bfhi(q0.w);
    aw += w0;
  }
  const float inv = 1.f / (aw + 1e-16f);
  const float4 pj0 = *(const float4*)&proj[(size_t)n * 128 + k * 8];
  const float4 pj1 = *(const float4*)&proj[(size_t)n * 128 + k * 8 + 4];
  const float4 b1a = *(const float4*)&b1[k * 8];
  const float4 b1b = *(const float4*)&b1[k * 8 + 4];
  const float4 bpa = *(const float4*)&bp[k * 8];
  const float4 bpb = *(const float4*)&bp[k * 8 + 4];
  float v[8];
  v[0] = acc[0] * inv + pj0.x + b1a.x + bpa.x;
  v[1] = acc[1] * inv + pj0.y + b1a.y + bpa.y;
  v[2] = acc[2] * inv + pj0.z + b1a.z + bpa.z;
  v[3] = acc[3] * inv + pj0.w + b1a.w + bpa.w;
  v[4] = acc[4] * inv + pj1.x + b1b.x + bpb.x;
  v[5] = acc[5] * inv + pj1.y + b1b.y + bpb.y;
  v[6] = acc[6] * inv + pj1.z + b1b.z + bpb.z;
  v[7] = acc[7] * inv + pj1.w + b1b.w + bpb.w;
  float p0 = 0.f, p1 = 0.f;
#pragma unroll
  for (int i = 0; i < 8; i++) {
    float vi = v[i] > 0.f ? v[i] : (__expf(v[i]) - 1.f);
    float2 w2 = *(const float2*)&W2[(k * 8 + i) * 2];
    p0 += vi * w2.x;
    p1 += vi * w2.y;
  }
#pragma unroll
  for (int off = 8; off; off >>= 1) {
    p0 += __shfl_xor(p0, off);
    p1 += __shfl_xor(p1, off);
  }
  if (k == 0) {
    h2[2 * n] = p0;
    h2[2 * n + 1] = p1;
    as2[n] = p0 * att_s2[0] + p1 * att_s2[1];
    ad2[n] = p0 * att_d2[0] + p1 * att_d2[1];
  }
}

// ---------------- layer-2 aggregation (16 lanes per node) ------------------
__global__ __launch_bounds__(256) void agg2(
    const float* __restrict__ h2, const float* __restrict__ as2,
    const float* __restrict__ ad2, const int* __restrict__ offsets,
    const int* __restrict__ sortedsrc, const float* __restrict__ b2,
    float* __restrict__ out, int N) {
  const int node = blockIdx.x * 16 + (threadIdx.x >> 4);
  const int lane = threadIdx.x & 15;
  const int begin = offsets[node], end = offsets[node + 1];
  const float ad = ad2[node];
  float acc0 = 0.f, acc1 = 0.f, aw = 0.f;
  for (int j = begin + lane; j < end; j += 16) {
    int s = sortedsrc[j];
    float e = as2[s] + ad;
    float w = __expf(e > 0.f ? e : NEG_SLOPE * e);
    float2 hh = *(const float2*)&h2[2 * s];
    acc0 += w * hh.x;
    acc1 += w * hh.y;
    aw += w;
  }
#pragma unroll
  for (int off = 8; off; off >>= 1) {
    acc0 += __shfl_xor(acc0, off);
    acc1 += __shfl_xor(acc1, off);
    aw += __shfl_xor(aw, off);
  }
  if (lane == 0) {
    float inv = 1.f / (aw + 1e-16f);
    out[2 * node] = acc0 * inv + b2[0];
    out[2 * node + 1] = acc1 * inv + b2[1];
  }
}

extern "C" void kernel_launch(void* const* d_in, const int* in_sizes, int n_in,
                              void* d_out, int out_size, void* d_ws,
                              size_t ws_size, hipStream_t stream) {
  const float* x = (const float*)d_in[0];
  const int* edge_index = (const int*)d_in[1];
  const float* W1 = (const float*)d_in[2];
  const float* att_src1 = (const float*)d_in[3];
  const float* att_dst1 = (const float*)d_in[4];
  const float* b1 = (const float*)d_in[5];
  const float* Wp = (const float*)d_in[6];
  const float* bp = (const float*)d_in[7];
  const float* W2 = (const float*)d_in[8];
  const float* att_src2 = (const float*)d_in[9];
  const float* att_dst2 = (const float*)d_in[10];
  const float* b2 = (const float*)d_in[11];
  float* out = (float*)d_out;

  const int N = in_sizes[0] / 768;
  const int E = in_sizes[1] / 2;
  const int Etot = E + N;
  const int* src = edge_index;
  const int* dst = edge_index + E;

  char* ws = (char*)d_ws;
  size_t off = 0;
  auto alloc = [&](size_t bytes) {
    size_t cur = off;
    off += (bytes + 255) & ~(size_t)255;
    return (void*)(ws + cur);
  };
  float* proj = (float*)alloc((size_t)N * 128 * 4);
  unsigned* h1bf = (unsigned*)alloc((size_t)N * 64 * 4);
  float* a_s1 = (float*)alloc((size_t)N * 8 * 4);
  float* a_d1 = (float*)alloc((size_t)N * 8 * 4);
  float* h2 = (float*)alloc((size_t)N * 2 * 4);
  float* as2 = (float*)alloc((size_t)N * 4);
  float* ad2 = (float*)alloc((size_t)N * 4);
  int* counts = (int*)alloc((size_t)N * 4);
  int* offsets = (int*)alloc(((size_t)N + 1) * 4);
  int* cursor = (int*)alloc((size_t)N * 4);
  int* bsum = (int*)alloc(256 * 4);
  int* sortedsrc = (int*)alloc((size_t)Etot * 4);
  short* Wt = (short*)alloc((size_t)256 * 768 * 2);

  // 0. weights -> bf16 B^T
  convert_w<<<768, 256, 0, stream>>>(W1, Wp, Wt);
  // 1. fused MFMA GEMM + attn1 (emits proj, h1bf, a_s1, a_d1)
  gemm_mfma<<<N / 128, 256, 0, stream>>>(x, Wt, att_src1, att_dst1, proj, h1bf,
                                         a_s1, a_d1);
  // 2. counting sort by dst (self loop placed in scan_c)
  init_counts<<<(N + 255) / 256, 256, 0, stream>>>(counts, N);
  hist_kernel<<<(E / 4 + 255) / 256, 256, 0, stream>>>(dst, counts, E);
  scan_a<<<N / 256, 256, 0, stream>>>(counts, offsets, bsum);
  scan_b<<<1, 256, 0, stream>>>(bsum);
  scan_c<<<N / 256, 256, 0, stream>>>(offsets, bsum, cursor, sortedsrc, N,
                                      Etot);
  scatter_edges<<<(E / 4 + 255) / 256, 256, 0, stream>>>(src, dst, cursor,
                                                         sortedsrc, E);
  // 3. layer-1 aggregation + residual + ELU + layer-2 features (fused)
  agg1_fused<<<N / 16, 256, 0, stream>>>((const uint4*)h1bf, proj, a_s1, a_d1,
                                         offsets, sortedsrc, b1, bp, W2,
                                         att_src2, att_dst2, h2, as2, ad2);
  // 4. layer-2 aggregation -> output
  agg2<<<N / 16, 256, 0, stream>>>(h2, as2, ad2, offsets, sortedsrc, b2, out,
                                   N);
}

// Round 5
// 568.065 us; speedup vs baseline: 1.0785x; 1.0785x over previous
//
#include <hip/hip_runtime.h>
#include <hip/hip_bf16.h>
#include <math.h>

#define NEG_SLOPE 0.2f

typedef __attribute__((ext_vector_type(8))) short short8;
typedef __attribute__((ext_vector_type(4))) float float4v;

__device__ __forceinline__ unsigned f2bf(float f) {
  unsigned u = __builtin_bit_cast(unsigned, f);
  return (u + 0x7fffu + ((u >> 16) & 1u)) >> 16;  // RNE
}
__device__ __forceinline__ float bflo(unsigned u) {
  return __builtin_bit_cast(float, u << 16);
}
__device__ __forceinline__ float bfhi(unsigned u) {
  return __builtin_bit_cast(float, u & 0xffff0000u);
}

// ---------------- weight pre-transpose: Wt[c][k] bf16, c in [0,256) --------
__global__ __launch_bounds__(256) void convert_w(const float* __restrict__ W1,
                                                 const float* __restrict__ Wp,
                                                 short* __restrict__ Wt) {
  int k = blockIdx.x;   // 0..767
  int c = threadIdx.x;  // 0..255
  float v = (c < 128) ? W1[k * 128 + c] : Wp[k * 128 + (c - 128)];
  Wt[(size_t)c * 768 + k] = (short)f2bf(v);
}

// ------- bf16 MFMA GEMM: emits h1bf (bf16-packed) + proj (fp32) ------------
// BM=64, BN=256, BK=32, 256 thr (4 waves). Waves 0-1: h1 cols -> h1bf pack.
// Waves 2-3: proj cols. No reductions in epilogue (R4 regression lesson).
__global__ __launch_bounds__(256) void gemm_mfma(const float* __restrict__ x,
                                                 const short* __restrict__ Wt,
                                                 float* __restrict__ proj,
                                                 unsigned* __restrict__ h1bf) {
  __shared__ short As[64][40];
  __shared__ short Bs[256][40];
  const int tid = threadIdx.x;
  const int wave = tid >> 6, lane = tid & 63;
  const int l15 = lane & 15, l4 = lane >> 4;
  const int row0 = blockIdx.x * 64;

  const int ar = tid >> 3;        // 0..31
  const int ak = (tid & 7) * 4;   // k offset (4 floats)
  const int bc = tid >> 2;        // 0..63
  const int bk = (tid & 3) * 8;   // k offset (8 bf16)

  float4v acc[4][4] = {};

  for (int k0 = 0; k0 < 768; k0 += 32) {
#pragma unroll
    for (int i = 0; i < 2; i++) {
      int r = i * 32 + ar;
      float4 f = *(const float4*)&x[(size_t)(row0 + r) * 768 + k0 + ak];
      uint2 p;
      p.x = f2bf(f.x) | (f2bf(f.y) << 16);
      p.y = f2bf(f.z) | (f2bf(f.w) << 16);
      *(uint2*)&As[r][ak] = p;
    }
#pragma unroll
    for (int i = 0; i < 4; i++) {
      int c = i * 64 + bc;
      uint4 v = *(const uint4*)&Wt[(size_t)c * 768 + k0 + bk];
      *(uint4*)&Bs[c][bk] = v;
    }
    __syncthreads();

    short8 afr[4];
#pragma unroll
    for (int rt = 0; rt < 4; rt++)
      afr[rt] = *(const short8*)&As[rt * 16 + l15][l4 * 8];
#pragma unroll
    for (int ct = 0; ct < 4; ct++) {
      short8 bfr = *(const short8*)&Bs[wave * 64 + ct * 16 + l15][l4 * 8];
#pragma unroll
      for (int rt = 0; rt < 4; rt++)
        acc[rt][ct] =
            __builtin_amdgcn_mfma_f32_16x16x32_bf16(afr[rt], bfr, acc[rt][ct], 0, 0, 0);
    }
    __syncthreads();
  }

  const int colbase = wave * 64;
  if (wave < 2) {
    // h1 columns -> packed bf16 (pair channels via 1 shuffle per element)
#pragma unroll
    for (int ct = 0; ct < 4; ct++) {
      const int c = colbase + ct * 16 + l15;
#pragma unroll
      for (int rt = 0; rt < 4; rt++) {
#pragma unroll
        for (int r = 0; r < 4; r++) {
          const int R = row0 + rt * 16 + l4 * 4 + r;
          unsigned u = f2bf(acc[rt][ct][r]);
          unsigned up = __shfl_xor(u, 1);
          if ((l15 & 1) == 0) h1bf[(size_t)R * 64 + (c >> 1)] = u | (up << 16);
        }
      }
    }
  } else {
    // proj columns
#pragma unroll
    for (int ct = 0; ct < 4; ct++) {
      const int c = colbase - 128 + ct * 16 + l15;
#pragma unroll
      for (int rt = 0; rt < 4; rt++) {
#pragma unroll
        for (int r = 0; r < 4; r++) {
          const int R = row0 + rt * 16 + l4 * 4 + r;
          proj[(size_t)R * 128 + c] = acc[rt][ct][r];
        }
      }
    }
  }
}

// ---------------- attention logits from h1bf (thread per node,head) --------
__global__ __launch_bounds__(256) void attn1b(const uint4* __restrict__ h1bf4,
                                              const float* __restrict__ att_src1,
                                              const float* __restrict__ att_dst1,
                                              float* __restrict__ a_s1,
                                              float* __restrict__ a_d1) {
  const int t = blockIdx.x * 256 + threadIdx.x;  // t in [0, N*8)
  const int n = t >> 3, h = t & 7;
  uint4 q0 = h1bf4[(size_t)n * 16 + h * 2];
  uint4 q1 = h1bf4[(size_t)n * 16 + h * 2 + 1];
  float v[16];
  v[0] = bflo(q0.x); v[1] = bfhi(q0.x); v[2] = bflo(q0.y); v[3] = bfhi(q0.y);
  v[4] = bflo(q0.z); v[5] = bfhi(q0.z); v[6] = bflo(q0.w); v[7] = bfhi(q0.w);
  v[8] = bflo(q1.x); v[9] = bfhi(q1.x); v[10] = bflo(q1.y); v[11] = bfhi(q1.y);
  v[12] = bflo(q1.z); v[13] = bfhi(q1.z); v[14] = bflo(q1.w); v[15] = bfhi(q1.w);
  float as = 0.f, ad = 0.f;
#pragma unroll
  for (int i = 0; i < 16; i++) {
    as += v[i] * att_src1[h * 16 + i];
    ad += v[i] * att_dst1[h * 16 + i];
  }
  a_s1[t] = as;
  a_d1[t] = ad;
}

// ---------------- counting sort of edges by dst ----------------------------
__global__ void init_counts(int* counts, int N) {
  int i = blockIdx.x * blockDim.x + threadIdx.x;
  if (i < N) counts[i] = 1;  // self loop
}

__global__ void hist_kernel(const int* __restrict__ dst, int* counts, int E) {
  int i = blockIdx.x * blockDim.x + threadIdx.x;
  int base = i * 4;
  if (base + 3 < E) {
    int4 d = *(const int4*)&dst[base];
    atomicAdd(&counts[d.x], 1);
    atomicAdd(&counts[d.y], 1);
    atomicAdd(&counts[d.z], 1);
    atomicAdd(&counts[d.w], 1);
  } else {
    for (int j = base; j < E; j++) atomicAdd(&counts[dst[j]], 1);
  }
}

__global__ __launch_bounds__(256) void scan_a(const int* __restrict__ counts,
                                              int* offsets, int* bsum) {
  __shared__ int s[256];
  int t = threadIdx.x, idx = blockIdx.x * 256 + t;
  int v = counts[idx];
  s[t] = v;
  __syncthreads();
  for (int d = 1; d < 256; d <<= 1) {
    int x = (t >= d) ? s[t - d] : 0;
    __syncthreads();
    s[t] += x;
    __syncthreads();
  }
  offsets[idx] = s[t] - v;
  if (t == 255) bsum[blockIdx.x] = s[t];
}

__global__ __launch_bounds__(256) void scan_b(int* bsum) {
  __shared__ int s[256];
  int t = threadIdx.x;
  int v = bsum[t];
  s[t] = v;
  __syncthreads();
  for (int d = 1; d < 256; d <<= 1) {
    int x = (t >= d) ? s[t - d] : 0;
    __syncthreads();
    s[t] += x;
    __syncthreads();
  }
  bsum[t] = s[t] - v;
}

// also places the self-loop at segment start (replaces scatter_self)
__global__ __launch_bounds__(256) void scan_c(int* offsets, const int* bsum,
                                              int* cursor, int* sortedsrc,
                                              int N, int Etot) {
  int t = threadIdx.x, idx = blockIdx.x * 256 + t;
  int off = offsets[idx] + bsum[blockIdx.x];
  offsets[idx] = off;
  sortedsrc[off] = idx;
  cursor[idx] = off + 1;
  if (idx == 0) offsets[N] = Etot;
}

__global__ void scatter_edges(const int* __restrict__ src,
                              const int* __restrict__ dst, int* cursor,
                              int* sortedsrc, int E) {
  int i = blockIdx.x * blockDim.x + threadIdx.x;
  int base = i * 4;
  if (base + 3 < E) {
    int4 s = *(const int4*)&src[base];
    int4 d = *(const int4*)&dst[base];
    sortedsrc[atomicAdd(&cursor[d.x], 1)] = s.x;
    sortedsrc[atomicAdd(&cursor[d.y], 1)] = s.y;
    sortedsrc[atomicAdd(&cursor[d.z], 1)] = s.z;
    sortedsrc[atomicAdd(&cursor[d.w], 1)] = s.w;
  } else {
    for (int j = base; j < E; j++)
      sortedsrc[atomicAdd(&cursor[dst[j]], 1)] = src[j];
  }
}

// ------- layer-1 aggregation + residual + ELU + layer-2 features -----------
// 16 nodes/block (256 thr), 16 lanes/node, 8 channels/lane (uint4 gathers),
// 4-deep edge pipeline.
__global__ __launch_bounds__(256) void agg1_fused(
    const uint4* __restrict__ h1bf4, const float* __restrict__ proj,
    const float* __restrict__ a_s1, const float* __restrict__ a_d1,
    const int* __restrict__ offsets, const int* __restrict__ sortedsrc,
    const float* __restrict__ b1, const float* __restrict__ bp,
    const float* __restrict__ W2, const float* __restrict__ att_s2,
    const float* __restrict__ att_d2, float* __restrict__ h2,
    float* __restrict__ as2, float* __restrict__ ad2) {
  const int t = threadIdx.x;
  const int n = blockIdx.x * 16 + (t >> 4);
  const int k = t & 15;   // lane within node: channels 8k..8k+7
  const int hd = k >> 1;  // head
  const float ad = a_d1[n * 8 + hd];
  const int begin = offsets[n], end = offsets[n + 1];
  float acc[8] = {};
  float aw = 0.f;
  int j = begin;
  for (; j + 4 <= end; j += 4) {
    int s0 = sortedsrc[j], s1 = sortedsrc[j + 1];
    int s2 = sortedsrc[j + 2], s3 = sortedsrc[j + 3];
    float e0 = a_s1[s0 * 8 + hd], e1 = a_s1[s1 * 8 + hd];
    float e2 = a_s1[s2 * 8 + hd], e3 = a_s1[s3 * 8 + hd];
    uint4 q0 = h1bf4[(size_t)s0 * 16 + k];
    uint4 q1 = h1bf4[(size_t)s1 * 16 + k];
    uint4 q2 = h1bf4[(size_t)s2 * 16 + k];
    uint4 q3 = h1bf4[(size_t)s3 * 16 + k];
    e0 += ad; e1 += ad; e2 += ad; e3 += ad;
    float w0 = __expf(e0 > 0.f ? e0 : NEG_SLOPE * e0);
    float w1 = __expf(e1 > 0.f ? e1 : NEG_SLOPE * e1);
    float w2 = __expf(e2 > 0.f ? e2 : NEG_SLOPE * e2);
    float w3 = __expf(e3 > 0.f ? e3 : NEG_SLOPE * e3);
    acc[0] += w0 * bflo(q0.x) + w1 * bflo(q1.x) + w2 * bflo(q2.x) + w3 * bflo(q3.x);
    acc[1] += w0 * bfhi(q0.x) + w1 * bfhi(q1.x) + w2 * bfhi(q2.x) + w3 * bfhi(q3.x);
    acc[2] += w0 * bflo(q0.y) + w1 * bflo(q1.y) + w2 * bflo(q2.y) + w3 * bflo(q3.y);
    acc[3] += w0 * bfhi(q0.y) + w1 * bfhi(q1.y) + w2 * bfhi(q2.y) + w3 * bfhi(q3.y);
    acc[4] += w0 * bflo(q0.z) + w1 * bflo(q1.z) + w2 * bflo(q2.z) + w3 * bflo(q3.z);
    acc[5] += w0 * bfhi(q0.z) + w1 * bfhi(q1.z) + w2 * bfhi(q2.z) + w3 * bfhi(q3.z);
    acc[6] += w0 * bflo(q0.w) + w1 * bflo(q1.w) + w2 * bflo(q2.w) + w3 * bflo(q3.w);
    acc[7] += w0 * bfhi(q0.w) + w1 * bfhi(q1.w) + w2 * bfhi(q2.w) + w3 * bfhi(q3.w);
    aw += (w0 + w1) + (w2 + w3);
  }
  for (; j < end; j++) {
    int s0 = sortedsrc[j];
    float e0 = a_s1[s0 * 8 + hd] + ad;
    uint4 q0 = h1bf4[(size_t)s0 * 16 + k];
    float w0 = __expf(e0 > 0.f ? e0 : NEG_SLOPE * e0);
    acc[0] += w0 * bflo(q0.x);
    acc[1] += w0 * bfhi(q0.x);
    acc[2] += w0 * bflo(q0.y);
    acc[3] += w0 * bfhi(q0.y);
    acc[4] += w0 * bflo(q0.z);
    acc[5] += w0 * bfhi(q0.z);
    acc[6] += w0 * bflo(q0.w);
    acc[7] += w0 * bfhi(q0.w);
    aw += w0;
  }
  const float inv = 1.f / (aw + 1e-16f);
  const float4 pj0 = *(const float4*)&proj[(size_t)n * 128 + k * 8];
  const float4 pj1 = *(const float4*)&proj[(size_t)n * 128 + k * 8 + 4];
  const float4 b1a = *(const float4*)&b1[k * 8];
  const float4 b1b = *(const float4*)&b1[k * 8 + 4];
  const float4 bpa = *(const float4*)&bp[k * 8];
  const float4 bpb = *(const float4*)&bp[k * 8 + 4];
  float v[8];
  v[0] = acc[0] * inv + pj0.x + b1a.x + bpa.x;
  v[1] = acc[1] * inv + pj0.y + b1a.y + bpa.y;
  v[2] = acc[2] * inv + pj0.z + b1a.z + bpa.z;
  v[3] = acc[3] * inv + pj0.w + b1a.w + bpa.w;
  v[4] = acc[4] * inv + pj1.x + b1b.x + bpb.x;
  v[5] = acc[5] * inv + pj1.y + b1b.y + bpb.y;
  v[6] = acc[6] * inv + pj1.z + b1b.z + bpb.z;
  v[7] = acc[7] * inv + pj1.w + b1b.w + bpb.w;
  float p0 = 0.f, p1 = 0.f;
#pragma unroll
  for (int i = 0; i < 8; i++) {
    float vi = v[i] > 0.f ? v[i] : (__expf(v[i]) - 1.f);
    float2 w2 = *(const float2*)&W2[(k * 8 + i) * 2];
    p0 += vi * w2.x;
    p1 += vi * w2.y;
  }
#pragma unroll
  for (int off = 8; off; off >>= 1) {
    p0 += __shfl_xor(p0, off);
    p1 += __shfl_xor(p1, off);
  }
  if (k == 0) {
    h2[2 * n] = p0;
    h2[2 * n + 1] = p1;
    as2[n] = p0 * att_s2[0] + p1 * att_s2[1];
    ad2[n] = p0 * att_d2[0] + p1 * att_d2[1];
  }
}

// ---------------- layer-2 aggregation (16 lanes per node) ------------------
__global__ __launch_bounds__(256) void agg2(
    const float* __restrict__ h2, const float* __restrict__ as2,
    const float* __restrict__ ad2, const int* __restrict__ offsets,
    const int* __restrict__ sortedsrc, const float* __restrict__ b2,
    float* __restrict__ out, int N) {
  const int node = blockIdx.x * 16 + (threadIdx.x >> 4);
  const int lane = threadIdx.x & 15;
  const int begin = offsets[node], end = offsets[node + 1];
  const float ad = ad2[node];
  float acc0 = 0.f, acc1 = 0.f, aw = 0.f;
  for (int j = begin + lane; j < end; j += 16) {
    int s = sortedsrc[j];
    float e = as2[s] + ad;
    float w = __expf(e > 0.f ? e : NEG_SLOPE * e);
    float2 hh = *(const float2*)&h2[2 * s];
    acc0 += w * hh.x;
    acc1 += w * hh.y;
    aw += w;
  }
#pragma unroll
  for (int off = 8; off; off >>= 1) {
    acc0 += __shfl_xor(acc0, off);
    acc1 += __shfl_xor(acc1, off);
    aw += __shfl_xor(aw, off);
  }
  if (lane == 0) {
    float inv = 1.f / (aw + 1e-16f);
    out[2 * node] = acc0 * inv + b2[0];
    out[2 * node + 1] = acc1 * inv + b2[1];
  }
}

extern "C" void kernel_launch(void* const* d_in, const int* in_sizes, int n_in,
                              void* d_out, int out_size, void* d_ws,
                              size_t ws_size, hipStream_t stream) {
  const float* x = (const float*)d_in[0];
  const int* edge_index = (const int*)d_in[1];
  const float* W1 = (const float*)d_in[2];
  const float* att_src1 = (const float*)d_in[3];
  const float* att_dst1 = (const float*)d_in[4];
  const float* b1 = (const float*)d_in[5];
  const float* Wp = (const float*)d_in[6];
  const float* bp = (const float*)d_in[7];
  const float* W2 = (const float*)d_in[8];
  const float* att_src2 = (const float*)d_in[9];
  const float* att_dst2 = (const float*)d_in[10];
  const float* b2 = (const float*)d_in[11];
  float* out = (float*)d_out;

  const int N = in_sizes[0] / 768;
  const int E = in_sizes[1] / 2;
  const int Etot = E + N;
  const int* src = edge_index;
  const int* dst = edge_index + E;

  char* ws = (char*)d_ws;
  size_t off = 0;
  auto alloc = [&](size_t bytes) {
    size_t cur = off;
    off += (bytes + 255) & ~(size_t)255;
    return (void*)(ws + cur);
  };
  float* proj = (float*)alloc((size_t)N * 128 * 4);
  unsigned* h1bf = (unsigned*)alloc((size_t)N * 64 * 4);
  float* a_s1 = (float*)alloc((size_t)N * 8 * 4);
  float* a_d1 = (float*)alloc((size_t)N * 8 * 4);
  float* h2 = (float*)alloc((size_t)N * 2 * 4);
  float* as2 = (float*)alloc((size_t)N * 4);
  float* ad2 = (float*)alloc((size_t)N * 4);
  int* counts = (int*)alloc((size_t)N * 4);
  int* offsets = (int*)alloc(((size_t)N + 1) * 4);
  int* cursor = (int*)alloc((size_t)N * 4);
  int* bsum = (int*)alloc(256 * 4);
  int* sortedsrc = (int*)alloc((size_t)Etot * 4);
  short* Wt = (short*)alloc((size_t)256 * 768 * 2);

  // 0. weights -> bf16 B^T
  convert_w<<<768, 256, 0, stream>>>(W1, Wp, Wt);
  // 1. MFMA GEMM (emits h1bf + proj)
  gemm_mfma<<<N / 64, 256, 0, stream>>>(x, Wt, proj, h1bf);
  // 2. attention logits from h1bf
  attn1b<<<N * 8 / 256, 256, 0, stream>>>((const uint4*)h1bf, att_src1,
                                          att_dst1, a_s1, a_d1);
  // 3. counting sort by dst (self loop placed in scan_c)
  init_counts<<<(N + 255) / 256, 256, 0, stream>>>(counts, N);
  hist_kernel<<<(E / 4 + 255) / 256, 256, 0, stream>>>(dst, counts, E);
  scan_a<<<N / 256, 256, 0, stream>>>(counts, offsets, bsum);
  scan_b<<<1, 256, 0, stream>>>(bsum);
  scan_c<<<N / 256, 256, 0, stream>>>(offsets, bsum, cursor, sortedsrc, N,
                                      Etot);
  scatter_edges<<<(E / 4 + 255) / 256, 256, 0, stream>>>(src, dst, cursor,
                                                         sortedsrc, E);
  // 4. layer-1 aggregation + residual + ELU + layer-2 features (fused)
  agg1_fused<<<N / 16, 256, 0, stream>>>((const uint4*)h1bf, proj, a_s1, a_d1,
                                         offsets, sortedsrc, b1, bp, W2,
                                         att_src2, att_dst2, h2, as2, ad2);
  // 5. layer-2 aggregation -> output
  agg2<<<N / 16, 256, 0, stream>>>(h2, as2, ad2, offsets, sortedsrc, b2, out,
                                   N);
}